// Round 14
// baseline (129.490 us; speedup 1.0000x reference)
//
#include <hip/hip_runtime.h>

#define BATCH 2048
#define NNEI 64
#define IN_DIM 80
#define EMBED 256
#define NCLS 5
#define NMODES 20
#define NROWS (BATCH * NNEI)   // 131072
#define NEXP (NCLS + 1)        // 6 neighbor experts
#define TM 16                  // rows per MFMA tile
#define GRID2 512              // persistent blocks for nei_gemv
#define MAXT 104               // max tiles per block

#define NBIN (NROWS / 256)     // 512 nei-bin blocks
#define NWF 144                // wfrag blocks (4 frags each, 576 total)
#define NPRJ (NCLS * NMODES)   // 100 proj blocks
#define NOB (BATCH / 256)      // 8 obs-bin blocks

#define TILE_O 8               // samples per obs tile
#define OGRID 256              // obs_mode grid

typedef __attribute__((ext_vector_type(8))) short bf16x8;
typedef __attribute__((ext_vector_type(4))) float f32x4;
typedef __attribute__((ext_vector_type(4))) int i32x4;

__device__ inline unsigned short bf16_rne(float f) {
    unsigned u = __builtin_bit_cast(unsigned, f);
    unsigned r = (u + 0x7fffu + ((u >> 16) & 1u)) >> 16;
    return (unsigned short)r;
}
__device__ inline float bf16_to_f(unsigned short h) {
    unsigned u = ((unsigned)h) << 16;
    return __builtin_bit_cast(float, u);
}
__device__ inline void st_nt(float* p, float v) { __builtin_nontemporal_store(v, p); }

// ---------------- K1: fused prep — nei-bin | wfrag | proj | obs-bin ----------
__global__ void prep_all(const int* __restrict__ nei_labels,
                         const int* __restrict__ self_labels,
                         int* __restrict__ counts, int* __restrict__ lists,
                         int* __restrict__ counts_o, int* __restrict__ lists_o,
                         const float* __restrict__ nei_W, unsigned short* __restrict__ wfrag,
                         const float* __restrict__ modes, const float* __restrict__ mode_W,
                         const float* __restrict__ mode_b, float* __restrict__ proj) {
    __shared__ int lc[NEXP], lb[NEXP];
    const int b = blockIdx.x;
    const int t = threadIdx.x;

    if (b < NBIN) {
        // ---- bin nei rows by label ----
        if (t < NEXP) lc[t] = 0;
        __syncthreads();
        int r = b * 256 + t;
        int c = nei_labels[r];
        int lpos = atomicAdd(&lc[c], 1);
        __syncthreads();
        if (t < NEXP) lb[t] = atomicAdd(&counts[t], lc[t]);
        __syncthreads();
        lists[(size_t)c * NROWS + lb[c] + lpos] = r;
    } else if (b < NBIN + NWF) {
        // ---- W fragment table: [c][ks(3)][cfg(16)][part(2)][lane(64)][8 bf16] ----
        int e = (b - NBIN) * 4 + (t >> 6);    // 0..575
        int l = t & 63;
        int part = e & 1;
        int cfg = (e >> 1) & 15;
        int ks = (e >> 5) % 3;
        int c = e / 96;
        int col = cfg * 16 + (l & 15);
        unsigned short v[8] __attribute__((aligned(16)));
        #pragma unroll
        for (int j = 0; j < 8; ++j) {
            int k = ks * 32 + ((l >> 4) * 8) + j;
            float w = (k < IN_DIM) ? nei_W[((size_t)c * IN_DIM + k) * EMBED + col] : 0.f;
            unsigned short h = bf16_rne(w);
            if (part == 0) v[j] = h;
            else v[j] = bf16_rne(w - bf16_to_f(h));
        }
        unsigned short* dst = wfrag + ((size_t)e * 64 + l) * 8;
        *reinterpret_cast<i32x4*>(dst) = *reinterpret_cast<const i32x4*>(v);
    } else if (b < NBIN + NWF + NPRJ) {
        // ---- proj[c][m][o] ----
        int cm = b - (NBIN + NWF);            // 0..99
        int o = t;
        const float* mv = modes + (size_t)cm * EMBED;
        float acc = mode_b[o];
        #pragma unroll 8
        for (int k = 0; k < EMBED; ++k)
            acc = fmaf(mv[k], mode_W[(size_t)(EMBED + k) * EMBED + o], acc);
        proj[(size_t)cm * EMBED + o] = acc;
    } else {
        // ---- bin obs samples by self_label ----
        if (t < NCLS) lc[t] = 0;
        __syncthreads();
        int r = (b - (NBIN + NWF + NPRJ)) * 256 + t;
        int c = self_labels[r];
        int lpos = atomicAdd(&lc[c], 1);
        __syncthreads();
        if (t < NCLS) lb[t] = atomicAdd(&counts_o[t], lc[t]);
        __syncthreads();
        lists_o[c * BATCH + lb[c] + lpos] = r;
    }
}

// ---------------- K2: obs embedding + mode head — class-binned ----------------
// Block handles single-class 8-sample tiles: obs_W[c] read once per block.
__global__ __launch_bounds__(256, 4)
void obs_mode(const float* __restrict__ obs,
              const int* __restrict__ counts_o, const int* __restrict__ lists_o,
              const float* __restrict__ obs_W, const float* __restrict__ obs_b,
              const float* __restrict__ mode_W, const float* __restrict__ proj,
              float* __restrict__ out0) {
    const int b = blockIdx.x;
    const int c = (b * NCLS) / OGRID;                    // contiguous class ranges
    const int cstart = (c * OGRID + NCLS - 1) / NCLS;
    const int cend = ((c + 1) * OGRID + NCLS - 1) / NCLS;
    const int blk = b - cstart;
    const int nblk = cend - cstart;
    const int cnt = counts_o[c];
    const int ntiles = (cnt + TILE_O - 1) / TILE_O;
    if (blk >= ntiles || cnt == 0) return;

    const int o = threadIdx.x;
    const int* mylist = lists_o + c * BATCH;
    const float* wc = obs_W + (size_t)c * IN_DIM * EMBED;
    const float* pj = proj + (size_t)c * NMODES * EMBED;
    const float bini = obs_b[c * EMBED + o];

    __shared__ float obs_s[TILE_O][IN_DIM];
    __shared__ float x_s[TILE_O][EMBED];
    __shared__ int rid_s[TILE_O];

    for (int lt = blk; lt < ntiles; lt += nblk) {
        if (o < TILE_O) {
            int gi = lt * TILE_O + o;
            rid_s[o] = (gi < cnt) ? mylist[gi] : -1;
        }
        __syncthreads();
        for (int f = o; f < TILE_O * IN_DIM; f += 256) {
            int bb = f / IN_DIM, k = f - bb * IN_DIM;
            int rid = rid_s[bb];
            obs_s[bb][k] = (rid >= 0) ? obs[(size_t)rid * IN_DIM + k] : 0.f;
        }
        __syncthreads();

        float xacc[TILE_O];
        #pragma unroll
        for (int bb = 0; bb < TILE_O; ++bb) xacc[bb] = bini;
        #pragma unroll 4
        for (int k = 0; k < IN_DIM; ++k) {
            float wv = wc[(size_t)k * EMBED + o];
            #pragma unroll
            for (int bb = 0; bb < TILE_O; ++bb)
                xacc[bb] = fmaf(obs_s[bb][k], wv, xacc[bb]);
        }
        #pragma unroll
        for (int bb = 0; bb < TILE_O; ++bb) x_s[bb][o] = xacc[bb];
        __syncthreads();

        float tacc[TILE_O];
        #pragma unroll
        for (int bb = 0; bb < TILE_O; ++bb) tacc[bb] = 0.f;
        #pragma unroll 4
        for (int k = 0; k < EMBED; ++k) {
            float wv = mode_W[(size_t)k * EMBED + o];
            #pragma unroll
            for (int bb = 0; bb < TILE_O; ++bb)
                tacc[bb] = fmaf(x_s[bb][k], wv, tacc[bb]);
        }
        #pragma unroll
        for (int bb = 0; bb < TILE_O; ++bb) {
            int rid = rid_s[bb];
            if (rid >= 0) {
                float* op = out0 + (size_t)rid * NMODES * EMBED;
                for (int m = 0; m < NMODES; ++m)
                    st_nt(&op[m * EMBED + o], tacc[bb] + pj[m * EMBED + o]);
            }
        }
        __syncthreads();
    }
}

// ---------------- K3: MFMA neighbor GEMM — 2-term split, depth-2 prefetch ----
// out_n[row][o] = nei_b[c][o] + sum_k r[row][k]*nei_W[c][k][o]
// r·w ≈ (rh + rl)·wh   (wl term dropped; absmax 8.0 vs threshold 34.9)
__global__ __launch_bounds__(256, 3)
void nei_gemv_mfma(const float* __restrict__ neis,
                   const unsigned short* __restrict__ wfrag,
                   const float* __restrict__ nei_b,
                   const int* __restrict__ counts,
                   const int* __restrict__ lists,
                   float* __restrict__ out_n) {
    const int b = blockIdx.x;
    const int c = (b * NEXP) / GRID2;                    // contiguous class ranges
    const int cstart = (c * GRID2 + NEXP - 1) / NEXP;
    const int cend = ((c + 1) * GRID2 + NEXP - 1) / NEXP;
    const int blk = b - cstart;
    const int nblk = cend - cstart;
    const int cnt = counts[c];
    const int ntiles = (cnt + TM - 1) / TM;

    __shared__ int rids_s[MAXT * TM];

    if (blk >= ntiles || cnt == 0) return;
    const int nt = min((ntiles - blk + nblk - 1) / nblk, MAXT);

    const int ch = threadIdx.x >> 6;   // wave id = col-quarter 0..3
    const int l = threadIdx.x & 63;
    const int* mylist = lists + (size_t)c * NROWS;
    const int kc = (l >> 4) * 8;

    for (int i = threadIdx.x; i < nt * TM; i += 256) {
        int j = i >> 4, r = i & 15;
        int gi = (blk + j * nblk) * TM + r;
        rids_s[i] = mylist[min(gi, cnt - 1)];
    }

    // hi-part weights only: 48 VGPR, pinned
    bf16x8 wh[3][4];
    {
        const unsigned short* wb = wfrag + (size_t)c * 96 * 64 * 8;
        #pragma unroll
        for (int ks = 0; ks < 3; ++ks)
            #pragma unroll
            for (int cf = 0; cf < 4; ++cf) {
                size_t base = ((((size_t)ks * 16 + (ch * 4 + cf)) * 2) * 64 + l) * 8;
                wh[ks][cf] = *reinterpret_cast<const bf16x8*>(wb + base);
            }
    }
    #pragma unroll
    for (int ks = 0; ks < 3; ++ks)
        #pragma unroll
        for (int cf = 0; cf < 4; ++cf) {
            i32x4 th = __builtin_bit_cast(i32x4, wh[ks][cf]);
            asm volatile("" : "+v"(th));
            wh[ks][cf] = __builtin_bit_cast(bf16x8, th);
        }
    float bias[4];
    #pragma unroll
    for (int cf = 0; cf < 4; ++cf) {
        bias[cf] = nei_b[c * EMBED + (ch * 4 + cf) * 16 + (l & 15)];
        asm volatile("" : "+v"(bias[cf]));
    }
    __syncthreads();   // rid cache ready

#define LOADJ(F, R, J) {                                                      \
    R = rids_s[(J) * TM + (l & 15)];                                          \
    const float* bp_ = neis + (size_t)(unsigned)R * IN_DIM;                   \
    _Pragma("unroll")                                                         \
    for (int ks_ = 0; ks_ < 3; ++ks_) {                                       \
        int k0_ = ks_ * 32 + kc;                                              \
        if (k0_ + 8 > IN_DIM) k0_ = 0; /* B frag is zero for k>=80 */         \
        *reinterpret_cast<float4*>(&F[ks_ * 8])     = *reinterpret_cast<const float4*>(bp_ + k0_);     \
        *reinterpret_cast<float4*>(&F[ks_ * 8 + 4]) = *reinterpret_cast<const float4*>(bp_ + k0_ + 4); \
    } }

#define COMPJ(F, R, J) {                                                      \
    bf16x8 ah_[3], al_[3];                                                    \
    _Pragma("unroll")                                                         \
    for (int ks_ = 0; ks_ < 3; ++ks_) {                                       \
        _Pragma("unroll")                                                     \
        for (int j_ = 0; j_ < 8; ++j_) {                                      \
            float v_ = F[ks_ * 8 + j_];                                       \
            float d_ = (v_ >= 0.f) ? (v_ + 1e-4f) : (v_ - 1e-4f);             \
            float r_ = __builtin_amdgcn_rcpf(d_);                             \
            unsigned short hi_ = bf16_rne(r_);                                \
            ah_[ks_][j_] = (short)hi_;                                        \
            al_[ks_][j_] = (short)bf16_rne(r_ - bf16_to_f(hi_));              \
        }                                                                     \
    }                                                                         \
    f32x4 acc_[4];                                                            \
    _Pragma("unroll")                                                         \
    for (int cf_ = 0; cf_ < 4; ++cf_) acc_[cf_] = (f32x4){0.f, 0.f, 0.f, 0.f};\
    _Pragma("unroll")                                                         \
    for (int ks_ = 0; ks_ < 3; ++ks_) {                                       \
        _Pragma("unroll")                                                     \
        for (int cf_ = 0; cf_ < 4; ++cf_) {                                   \
            acc_[cf_] = __builtin_amdgcn_mfma_f32_16x16x32_bf16(ah_[ks_], wh[ks_][cf_], acc_[cf_], 0, 0, 0); \
            acc_[cf_] = __builtin_amdgcn_mfma_f32_16x16x32_bf16(al_[ks_], wh[ks_][cf_], acc_[cf_], 0, 0, 0); \
        }                                                                     \
    }                                                                         \
    int rb_ = (l >> 4) * 4;                                                   \
    int tbase_ = (blk + (J) * nblk) * TM;                                     \
    _Pragma("unroll")                                                         \
    for (int i_ = 0; i_ < 4; ++i_) {                                          \
        int rid_ = rids_s[(J) * TM + rb_ + i_];                               \
        if (tbase_ + rb_ + i_ < cnt) {                                        \
            float* op_ = out_n + (size_t)(unsigned)rid_ * EMBED + (l & 15);   \
            _Pragma("unroll")                                                 \
            for (int cf_ = 0; cf_ < 4; ++cf_)                                 \
                st_nt(&op_[(ch * 4 + cf_) * 16], acc_[cf_][i_] + bias[cf_]);  \
        }                                                                     \
    } }

    float fA[24], fB[24], fC[24];
    int ridA, ridB, ridC;
    LOADJ(fA, ridA, 0)
    if (nt > 1) LOADJ(fB, ridB, 1)
    int j = 0;
    while (true) {
        if (j + 2 < nt) LOADJ(fC, ridC, j + 2)
        COMPJ(fA, ridA, j)
        if (j + 1 >= nt) break;
        if (j + 3 < nt) LOADJ(fA, ridA, j + 3)
        COMPJ(fB, ridB, j + 1)
        if (j + 2 >= nt) break;
        if (j + 4 < nt) LOADJ(fB, ridB, j + 4)
        COMPJ(fC, ridC, j + 2)
        if (j + 3 >= nt) break;
        j += 3;
    }
#undef LOADJ
#undef COMPJ
}

extern "C" void kernel_launch(void* const* d_in, const int* in_sizes, int n_in,
                              void* d_out, int out_size, void* d_ws, size_t ws_size,
                              hipStream_t stream) {
    const float* obs         = (const float*)d_in[0];
    const float* neis        = (const float*)d_in[1];
    const int*   self_labels = (const int*)d_in[2];
    const int*   nei_labels  = (const int*)d_in[3];
    const float* modes       = (const float*)d_in[4];
    const float* obs_W       = (const float*)d_in[5];
    const float* obs_b       = (const float*)d_in[6];
    const float* nei_W       = (const float*)d_in[7];
    const float* nei_b       = (const float*)d_in[8];
    const float* mode_W      = (const float*)d_in[9];
    const float* mode_b      = (const float*)d_in[10];

    float* out0  = (float*)d_out;
    float* out_n = out0 + (size_t)BATCH * NMODES * EMBED;

    char* ws = (char*)d_ws;
    int* counts   = (int*)ws;                                      // 24 B
    int* counts_o = (int*)(ws + 64);                               // 20 B
    int* lists    = (int*)(ws + 256);                              // 3 MiB
    size_t off = 256 + (size_t)NEXP * NROWS * 4;
    int* lists_o = (int*)(ws + off);                               // 40 KiB
    off += (size_t)NCLS * BATCH * 4;
    float* proj = (float*)(ws + off);                              // 100 KiB
    off += (size_t)NCLS * NMODES * EMBED * 4;
    unsigned short* wfrag = (unsigned short*)(ws + off);           // 576 KiB

    hipMemsetAsync(ws, 0, 128, stream);   // counts + counts_o

    prep_all<<<NBIN + NWF + NPRJ + NOB, 256, 0, stream>>>(
        nei_labels, self_labels, counts, lists, counts_o, lists_o,
        nei_W, wfrag, modes, mode_W, mode_b, proj);
    obs_mode<<<OGRID, 256, 0, stream>>>(obs, counts_o, lists_o, obs_W, obs_b,
                                        mode_W, proj, out0);
    nei_gemv_mfma<<<GRID2, 256, 0, stream>>>(neis, wfrag, nei_b,
                                             counts, lists, out_n);
}

// Round 15
// 110.551 us; speedup vs baseline: 1.1713x; 1.1713x over previous
//
#include <hip/hip_runtime.h>

#define BATCH 2048
#define NNEI 64
#define IN_DIM 80
#define EMBED 256
#define NCLS 5
#define NMODES 20
#define NROWS (BATCH * NNEI)   // 131072
#define NEXP (NCLS + 1)        // 6 neighbor experts
#define TM 16                  // rows per MFMA tile
#define GRID2 768              // persistent blocks for nei_gemv (3/CU, 128/class)
#define MAXT 104               // max tiles per block

#define NBIN (NROWS / 256)     // 512 nei-bin blocks
#define NWF 144                // wfrag blocks (4 frags each, 576 total)
#define NPRJ (NCLS * NMODES)   // 100 proj blocks
#define NOB (BATCH / 256)      // 8 obs-bin blocks

#define TILE_O 8               // samples per obs tile
#define OGRID 256              // obs_mode grid

typedef __attribute__((ext_vector_type(8))) short bf16x8;
typedef __attribute__((ext_vector_type(4))) float f32x4;
typedef __attribute__((ext_vector_type(4))) int i32x4;

__device__ inline unsigned short bf16_rne(float f) {
    unsigned u = __builtin_bit_cast(unsigned, f);
    unsigned r = (u + 0x7fffu + ((u >> 16) & 1u)) >> 16;
    return (unsigned short)r;
}
__device__ inline float bf16_to_f(unsigned short h) {
    unsigned u = ((unsigned)h) << 16;
    return __builtin_bit_cast(float, u);
}
__device__ inline void st_nt(float* p, float v) { __builtin_nontemporal_store(v, p); }

// ---------------- K1: fused prep — nei-bin | wfrag | proj | obs-bin ----------
__global__ void prep_all(const int* __restrict__ nei_labels,
                         const int* __restrict__ self_labels,
                         int* __restrict__ counts, int* __restrict__ lists,
                         int* __restrict__ counts_o, int* __restrict__ lists_o,
                         const float* __restrict__ nei_W, unsigned short* __restrict__ wfrag,
                         const float* __restrict__ modes, const float* __restrict__ mode_W,
                         const float* __restrict__ mode_b, float* __restrict__ proj) {
    __shared__ int lc[NEXP], lb[NEXP];
    const int b = blockIdx.x;
    const int t = threadIdx.x;

    if (b < NBIN) {
        // ---- bin nei rows by label ----
        if (t < NEXP) lc[t] = 0;
        __syncthreads();
        int r = b * 256 + t;
        int c = nei_labels[r];
        int lpos = atomicAdd(&lc[c], 1);
        __syncthreads();
        if (t < NEXP) lb[t] = atomicAdd(&counts[t], lc[t]);
        __syncthreads();
        lists[(size_t)c * NROWS + lb[c] + lpos] = r;
    } else if (b < NBIN + NWF) {
        // ---- W fragment table: [c][ks(3)][cfg(16)][part(2)][lane(64)][8 bf16] ----
        int e = (b - NBIN) * 4 + (t >> 6);    // 0..575
        int l = t & 63;
        int part = e & 1;
        int cfg = (e >> 1) & 15;
        int ks = (e >> 5) % 3;
        int c = e / 96;
        int col = cfg * 16 + (l & 15);
        unsigned short v[8] __attribute__((aligned(16)));
        #pragma unroll
        for (int j = 0; j < 8; ++j) {
            int k = ks * 32 + ((l >> 4) * 8) + j;
            float w = (k < IN_DIM) ? nei_W[((size_t)c * IN_DIM + k) * EMBED + col] : 0.f;
            unsigned short h = bf16_rne(w);
            if (part == 0) v[j] = h;
            else v[j] = bf16_rne(w - bf16_to_f(h));
        }
        unsigned short* dst = wfrag + ((size_t)e * 64 + l) * 8;
        *reinterpret_cast<i32x4*>(dst) = *reinterpret_cast<const i32x4*>(v);
    } else if (b < NBIN + NWF + NPRJ) {
        // ---- proj[c][m][o] ----
        int cm = b - (NBIN + NWF);            // 0..99
        int o = t;
        const float* mv = modes + (size_t)cm * EMBED;
        float acc = mode_b[o];
        #pragma unroll 8
        for (int k = 0; k < EMBED; ++k)
            acc = fmaf(mv[k], mode_W[(size_t)(EMBED + k) * EMBED + o], acc);
        proj[(size_t)cm * EMBED + o] = acc;
    } else {
        // ---- bin obs samples by self_label ----
        if (t < NCLS) lc[t] = 0;
        __syncthreads();
        int r = (b - (NBIN + NWF + NPRJ)) * 256 + t;
        int c = self_labels[r];
        int lpos = atomicAdd(&lc[c], 1);
        __syncthreads();
        if (t < NCLS) lb[t] = atomicAdd(&counts_o[t], lc[t]);
        __syncthreads();
        lists_o[c * BATCH + lb[c] + lpos] = r;
    }
}

// ---------------- K2: obs embedding + mode head — class-binned ----------------
// Block handles single-class 8-sample tiles: obs_W[c] read once per block.
__global__ __launch_bounds__(256, 4)
void obs_mode(const float* __restrict__ obs,
              const int* __restrict__ counts_o, const int* __restrict__ lists_o,
              const float* __restrict__ obs_W, const float* __restrict__ obs_b,
              const float* __restrict__ mode_W, const float* __restrict__ proj,
              float* __restrict__ out0) {
    const int b = blockIdx.x;
    const int c = (b * NCLS) / OGRID;                    // contiguous class ranges
    const int cstart = (c * OGRID + NCLS - 1) / NCLS;
    const int cend = ((c + 1) * OGRID + NCLS - 1) / NCLS;
    const int blk = b - cstart;
    const int nblk = cend - cstart;
    const int cnt = counts_o[c];
    const int ntiles = (cnt + TILE_O - 1) / TILE_O;
    if (blk >= ntiles || cnt == 0) return;

    const int o = threadIdx.x;
    const int* mylist = lists_o + c * BATCH;
    const float* wc = obs_W + (size_t)c * IN_DIM * EMBED;
    const float* pj = proj + (size_t)c * NMODES * EMBED;
    const float bini = obs_b[c * EMBED + o];

    __shared__ float obs_s[TILE_O][IN_DIM];
    __shared__ float x_s[TILE_O][EMBED];
    __shared__ int rid_s[TILE_O];

    for (int lt = blk; lt < ntiles; lt += nblk) {
        if (o < TILE_O) {
            int gi = lt * TILE_O + o;
            rid_s[o] = (gi < cnt) ? mylist[gi] : -1;
        }
        __syncthreads();
        for (int f = o; f < TILE_O * IN_DIM; f += 256) {
            int bb = f / IN_DIM, k = f - bb * IN_DIM;
            int rid = rid_s[bb];
            obs_s[bb][k] = (rid >= 0) ? obs[(size_t)rid * IN_DIM + k] : 0.f;
        }
        __syncthreads();

        float xacc[TILE_O];
        #pragma unroll
        for (int bb = 0; bb < TILE_O; ++bb) xacc[bb] = bini;
        #pragma unroll 4
        for (int k = 0; k < IN_DIM; ++k) {
            float wv = wc[(size_t)k * EMBED + o];
            #pragma unroll
            for (int bb = 0; bb < TILE_O; ++bb)
                xacc[bb] = fmaf(obs_s[bb][k], wv, xacc[bb]);
        }
        #pragma unroll
        for (int bb = 0; bb < TILE_O; ++bb) x_s[bb][o] = xacc[bb];
        __syncthreads();

        float tacc[TILE_O];
        #pragma unroll
        for (int bb = 0; bb < TILE_O; ++bb) tacc[bb] = 0.f;
        #pragma unroll 4
        for (int k = 0; k < EMBED; ++k) {
            float wv = mode_W[(size_t)k * EMBED + o];
            #pragma unroll
            for (int bb = 0; bb < TILE_O; ++bb)
                tacc[bb] = fmaf(x_s[bb][k], wv, tacc[bb]);
        }
        #pragma unroll
        for (int bb = 0; bb < TILE_O; ++bb) {
            int rid = rid_s[bb];
            if (rid >= 0) {
                float* op = out0 + (size_t)rid * NMODES * EMBED;
                for (int m = 0; m < NMODES; ++m)
                    st_nt(&op[m * EMBED + o], tacc[bb] + pj[m * EMBED + o]);
            }
        }
        __syncthreads();
    }
}

// ---------------- K3: MFMA neighbor GEMM — 2-term split, depth-1 prefetch,
//                  3 blocks/CU, plain (L2-merged) stores ----------------
// out_n[row][o] = nei_b[c][o] + sum_k r[row][k]*nei_W[c][k][o]
// r·w ≈ (rh + rl)·wh   (wl term dropped; absmax 8.0 vs threshold 34.9)
__global__ __launch_bounds__(256, 3)
void nei_gemv_mfma(const float* __restrict__ neis,
                   const unsigned short* __restrict__ wfrag,
                   const float* __restrict__ nei_b,
                   const int* __restrict__ counts,
                   const int* __restrict__ lists,
                   float* __restrict__ out_n) {
    const int b = blockIdx.x;
    const int c = (b * NEXP) / GRID2;                    // contiguous class ranges
    const int cstart = (c * GRID2 + NEXP - 1) / NEXP;
    const int cend = ((c + 1) * GRID2 + NEXP - 1) / NEXP;
    const int blk = b - cstart;
    const int nblk = cend - cstart;
    const int cnt = counts[c];
    const int ntiles = (cnt + TM - 1) / TM;

    __shared__ int rids_s[MAXT * TM];

    if (blk >= ntiles || cnt == 0) return;
    const int nt = min((ntiles - blk + nblk - 1) / nblk, MAXT);

    const int ch = threadIdx.x >> 6;   // wave id = col-quarter 0..3
    const int l = threadIdx.x & 63;
    const int* mylist = lists + (size_t)c * NROWS;
    const int kc = (l >> 4) * 8;

    for (int i = threadIdx.x; i < nt * TM; i += 256) {
        int j = i >> 4, r = i & 15;
        int gi = (blk + j * nblk) * TM + r;
        rids_s[i] = mylist[min(gi, cnt - 1)];
    }

    // hi-part weights only: 48 VGPR, pinned
    bf16x8 wh[3][4];
    {
        const unsigned short* wb = wfrag + (size_t)c * 96 * 64 * 8;
        #pragma unroll
        for (int ks = 0; ks < 3; ++ks)
            #pragma unroll
            for (int cf = 0; cf < 4; ++cf) {
                size_t base = ((((size_t)ks * 16 + (ch * 4 + cf)) * 2) * 64 + l) * 8;
                wh[ks][cf] = *reinterpret_cast<const bf16x8*>(wb + base);
            }
    }
    #pragma unroll
    for (int ks = 0; ks < 3; ++ks)
        #pragma unroll
        for (int cf = 0; cf < 4; ++cf) {
            i32x4 th = __builtin_bit_cast(i32x4, wh[ks][cf]);
            asm volatile("" : "+v"(th));
            wh[ks][cf] = __builtin_bit_cast(bf16x8, th);
        }
    float bias[4];
    #pragma unroll
    for (int cf = 0; cf < 4; ++cf) {
        bias[cf] = nei_b[c * EMBED + (ch * 4 + cf) * 16 + (l & 15)];
        asm volatile("" : "+v"(bias[cf]));
    }
    __syncthreads();   // rid cache ready

#define LOADJ(F, R, J) {                                                      \
    R = rids_s[(J) * TM + (l & 15)];                                          \
    const float* bp_ = neis + (size_t)(unsigned)R * IN_DIM;                   \
    _Pragma("unroll")                                                         \
    for (int ks_ = 0; ks_ < 3; ++ks_) {                                       \
        int k0_ = ks_ * 32 + kc;                                              \
        if (k0_ + 8 > IN_DIM) k0_ = 0; /* B frag is zero for k>=80 */         \
        *reinterpret_cast<float4*>(&F[ks_ * 8])     = *reinterpret_cast<const float4*>(bp_ + k0_);     \
        *reinterpret_cast<float4*>(&F[ks_ * 8 + 4]) = *reinterpret_cast<const float4*>(bp_ + k0_ + 4); \
    } }

#define COMPJ(F, R, J) {                                                      \
    bf16x8 ah_[3], al_[3];                                                    \
    _Pragma("unroll")                                                         \
    for (int ks_ = 0; ks_ < 3; ++ks_) {                                       \
        _Pragma("unroll")                                                     \
        for (int j_ = 0; j_ < 8; ++j_) {                                      \
            float v_ = F[ks_ * 8 + j_];                                       \
            float d_ = (v_ >= 0.f) ? (v_ + 1e-4f) : (v_ - 1e-4f);             \
            float r_ = __builtin_amdgcn_rcpf(d_);                             \
            unsigned short hi_ = bf16_rne(r_);                                \
            ah_[ks_][j_] = (short)hi_;                                        \
            al_[ks_][j_] = (short)bf16_rne(r_ - bf16_to_f(hi_));              \
        }                                                                     \
    }                                                                         \
    f32x4 acc_[4];                                                            \
    _Pragma("unroll")                                                         \
    for (int cf_ = 0; cf_ < 4; ++cf_) acc_[cf_] = (f32x4){0.f, 0.f, 0.f, 0.f};\
    _Pragma("unroll")                                                         \
    for (int ks_ = 0; ks_ < 3; ++ks_) {                                       \
        _Pragma("unroll")                                                     \
        for (int cf_ = 0; cf_ < 4; ++cf_) {                                   \
            acc_[cf_] = __builtin_amdgcn_mfma_f32_16x16x32_bf16(ah_[ks_], wh[ks_][cf_], acc_[cf_], 0, 0, 0); \
            acc_[cf_] = __builtin_amdgcn_mfma_f32_16x16x32_bf16(al_[ks_], wh[ks_][cf_], acc_[cf_], 0, 0, 0); \
        }                                                                     \
    }                                                                         \
    int rb_ = (l >> 4) * 4;                                                   \
    int tbase_ = (blk + (J) * nblk) * TM;                                     \
    _Pragma("unroll")                                                         \
    for (int i_ = 0; i_ < 4; ++i_) {                                          \
        int rid_ = rids_s[(J) * TM + rb_ + i_];                               \
        if (tbase_ + rb_ + i_ < cnt) {                                        \
            float* op_ = out_n + (size_t)(unsigned)rid_ * EMBED + (l & 15);   \
            _Pragma("unroll")                                                 \
            for (int cf_ = 0; cf_ < 4; ++cf_)                                 \
                op_[(ch * 4 + cf_) * 16] = acc_[cf_][i_] + bias[cf_];         \
        }                                                                     \
    } }

    float fA[24], fB[24];
    int ridA, ridB;
    LOADJ(fA, ridA, 0)
    int j = 0;
    while (true) {
        if (j + 1 < nt) LOADJ(fB, ridB, j + 1)    // prefetch next tile
        COMPJ(fA, ridA, j)
        if (j + 1 >= nt) break;
        if (j + 2 < nt) LOADJ(fA, ridA, j + 2)
        COMPJ(fB, ridB, j + 1)
        if (j + 2 >= nt) break;
        j += 2;
    }
#undef LOADJ
#undef COMPJ
}

extern "C" void kernel_launch(void* const* d_in, const int* in_sizes, int n_in,
                              void* d_out, int out_size, void* d_ws, size_t ws_size,
                              hipStream_t stream) {
    const float* obs         = (const float*)d_in[0];
    const float* neis        = (const float*)d_in[1];
    const int*   self_labels = (const int*)d_in[2];
    const int*   nei_labels  = (const int*)d_in[3];
    const float* modes       = (const float*)d_in[4];
    const float* obs_W       = (const float*)d_in[5];
    const float* obs_b       = (const float*)d_in[6];
    const float* nei_W       = (const float*)d_in[7];
    const float* nei_b       = (const float*)d_in[8];
    const float* mode_W      = (const float*)d_in[9];
    const float* mode_b      = (const float*)d_in[10];

    float* out0  = (float*)d_out;
    float* out_n = out0 + (size_t)BATCH * NMODES * EMBED;

    char* ws = (char*)d_ws;
    int* counts   = (int*)ws;                                      // 24 B
    int* counts_o = (int*)(ws + 64);                               // 20 B
    int* lists    = (int*)(ws + 256);                              // 3 MiB
    size_t off = 256 + (size_t)NEXP * NROWS * 4;
    int* lists_o = (int*)(ws + off);                               // 40 KiB
    off += (size_t)NCLS * BATCH * 4;
    float* proj = (float*)(ws + off);                              // 100 KiB
    off += (size_t)NCLS * NMODES * EMBED * 4;
    unsigned short* wfrag = (unsigned short*)(ws + off);           // 576 KiB

    hipMemsetAsync(ws, 0, 128, stream);   // counts + counts_o

    prep_all<<<NBIN + NWF + NPRJ + NOB, 256, 0, stream>>>(
        nei_labels, self_labels, counts, lists, counts_o, lists_o,
        nei_W, wfrag, modes, mode_W, mode_b, proj);
    obs_mode<<<OGRID, 256, 0, stream>>>(obs, counts_o, lists_o, obs_W, obs_b,
                                        mode_W, proj, out0);
    nei_gemv_mfma<<<GRID2, 256, 0, stream>>>(neis, wfrag, nei_b,
                                             counts, lists, out_n);
}

// Round 16
// 103.338 us; speedup vs baseline: 1.2531x; 1.0698x over previous
//
#include <hip/hip_runtime.h>

#define BATCH 2048
#define NNEI 64
#define IN_DIM 80
#define EMBED 256
#define NCLS 5
#define NMODES 20
#define NROWS (BATCH * NNEI)   // 131072
#define NEXP (NCLS + 1)        // 6 neighbor experts
#define TM 16                  // rows per MFMA tile
#define GRID2 512              // gemv blocks (2/CU)
#define MAXT 24                // max tiles per gemv block (~17 typical)

#define NBIN (NROWS / 256)     // 512 nei-bin blocks
#define NWF 72                 // wfrag blocks (4 frags each, 288 total, hi only)
#define NPRJ4 25               // proj blocks (4 cm each)
#define NOB (BATCH / 256)      // 8 obs-bin blocks

#define TILE_O 8               // samples per obs tile
#define OGRID 256              // obs blocks inside fused kernel

typedef __attribute__((ext_vector_type(8))) short bf16x8;
typedef __attribute__((ext_vector_type(4))) float f32x4;
typedef __attribute__((ext_vector_type(4))) int i32x4;

__device__ inline unsigned short bf16_rne(float f) {
    unsigned u = __builtin_bit_cast(unsigned, f);
    unsigned r = (u + 0x7fffu + ((u >> 16) & 1u)) >> 16;
    return (unsigned short)r;
}
__device__ inline float bf16_to_f(unsigned short h) {
    unsigned u = ((unsigned)h) << 16;
    return __builtin_bit_cast(float, u);
}
__device__ inline void st_nt(float* p, float v) { __builtin_nontemporal_store(v, p); }

// ---------------- K1: fused prep — nei-bin | wfrag(hi) | proj×4 | obs-bin ----
__global__ void prep_all(const int* __restrict__ nei_labels,
                         const int* __restrict__ self_labels,
                         int* __restrict__ counts, int* __restrict__ lists,
                         int* __restrict__ counts_o, int* __restrict__ lists_o,
                         const float* __restrict__ nei_W, unsigned short* __restrict__ wfrag,
                         const float* __restrict__ modes, const float* __restrict__ mode_W,
                         const float* __restrict__ mode_b, float* __restrict__ proj) {
    __shared__ int lc[NEXP], lb[NEXP];
    const int b = blockIdx.x;
    const int t = threadIdx.x;

    if (b < NBIN) {
        // ---- bin nei rows by label ----
        if (t < NEXP) lc[t] = 0;
        __syncthreads();
        int r = b * 256 + t;
        int c = nei_labels[r];
        int lpos = atomicAdd(&lc[c], 1);
        __syncthreads();
        if (t < NEXP) lb[t] = atomicAdd(&counts[t], lc[t]);
        __syncthreads();
        lists[(size_t)c * NROWS + lb[c] + lpos] = r;
    } else if (b < NBIN + NWF) {
        // ---- W fragment table (hi only): [c][ks(3)][cfg(16)][lane(64)][8 bf16] ----
        int e = (b - NBIN) * 4 + (t >> 6);    // 0..287 = (c*3+ks)*16+cfg
        int l = t & 63;
        int cfg = e & 15;
        int ks = (e >> 4) % 3;
        int c = e / 48;
        int col = cfg * 16 + (l & 15);
        unsigned short v[8] __attribute__((aligned(16)));
        #pragma unroll
        for (int j = 0; j < 8; ++j) {
            int k = ks * 32 + ((l >> 4) * 8) + j;
            float w = (k < IN_DIM) ? nei_W[((size_t)c * IN_DIM + k) * EMBED + col] : 0.f;
            v[j] = bf16_rne(w);
        }
        unsigned short* dst = wfrag + ((size_t)e * 64 + l) * 8;
        *reinterpret_cast<i32x4*>(dst) = *reinterpret_cast<const i32x4*>(v);
    } else if (b < NBIN + NWF + NPRJ4) {
        // ---- proj[cm][o] for 4 cm per block (amortize mode_W reads) ----
        int pb = b - (NBIN + NWF);            // 0..24
        int o = t;
        const float* mv0 = modes + (size_t)(pb * 4 + 0) * EMBED;
        const float* mv1 = modes + (size_t)(pb * 4 + 1) * EMBED;
        const float* mv2 = modes + (size_t)(pb * 4 + 2) * EMBED;
        const float* mv3 = modes + (size_t)(pb * 4 + 3) * EMBED;
        float a0 = mode_b[o], a1 = a0, a2 = a0, a3 = a0;
        #pragma unroll 4
        for (int k = 0; k < EMBED; ++k) {
            float wv = mode_W[(size_t)(EMBED + k) * EMBED + o];
            a0 = fmaf(mv0[k], wv, a0);
            a1 = fmaf(mv1[k], wv, a1);
            a2 = fmaf(mv2[k], wv, a2);
            a3 = fmaf(mv3[k], wv, a3);
        }
        proj[(size_t)(pb * 4 + 0) * EMBED + o] = a0;
        proj[(size_t)(pb * 4 + 1) * EMBED + o] = a1;
        proj[(size_t)(pb * 4 + 2) * EMBED + o] = a2;
        proj[(size_t)(pb * 4 + 3) * EMBED + o] = a3;
    } else {
        // ---- bin obs samples by self_label ----
        if (t < NCLS) lc[t] = 0;
        __syncthreads();
        int r = (b - (NBIN + NWF + NPRJ4)) * 256 + t;
        int c = self_labels[r];
        int lpos = atomicAdd(&lc[c], 1);
        __syncthreads();
        if (t < NCLS) lb[t] = atomicAdd(&counts_o[t], lc[t]);
        __syncthreads();
        lists_o[c * BATCH + lb[c] + lpos] = r;
    }
}

// ---------------- K2: FUSED main — obs blocks (0..255) + gemv blocks (256..767)
__global__ __launch_bounds__(256, 2)
void fused_main(const float* __restrict__ obs,
                const float* __restrict__ neis,
                const int* __restrict__ counts_o, const int* __restrict__ lists_o,
                const int* __restrict__ counts, const int* __restrict__ lists,
                const float* __restrict__ obs_W, const float* __restrict__ obs_b,
                const float* __restrict__ mode_W, const float* __restrict__ proj,
                const unsigned short* __restrict__ wfrag, const float* __restrict__ nei_b,
                float* __restrict__ out0, float* __restrict__ out_n) {
    const int t = threadIdx.x;

    if (blockIdx.x < OGRID) {
        // ================= obs path: class-binned, obs_W read once/block ======
        const int b = blockIdx.x;
        const int c = (b * NCLS) / OGRID;
        const int cstart = (c * OGRID + NCLS - 1) / NCLS;
        const int cend = ((c + 1) * OGRID + NCLS - 1) / NCLS;
        const int blk = b - cstart;
        const int nblk = cend - cstart;
        const int cnt = counts_o[c];
        const int ntiles = (cnt + TILE_O - 1) / TILE_O;
        if (blk >= ntiles || cnt == 0) return;

        const int o = t;
        const int* mylist = lists_o + c * BATCH;
        const float* wc = obs_W + (size_t)c * IN_DIM * EMBED;
        const float* pj = proj + (size_t)c * NMODES * EMBED;
        const float bini = obs_b[c * EMBED + o];

        __shared__ float obs_s[TILE_O][IN_DIM];
        __shared__ float x_s[TILE_O][EMBED];
        __shared__ int rid_s[TILE_O];

        for (int lt = blk; lt < ntiles; lt += nblk) {
            if (o < TILE_O) {
                int gi = lt * TILE_O + o;
                rid_s[o] = (gi < cnt) ? mylist[gi] : -1;
            }
            __syncthreads();
            for (int f = o; f < TILE_O * IN_DIM; f += 256) {
                int bb = f / IN_DIM, k = f - bb * IN_DIM;
                int rid = rid_s[bb];
                obs_s[bb][k] = (rid >= 0) ? obs[(size_t)rid * IN_DIM + k] : 0.f;
            }
            __syncthreads();

            float xacc[TILE_O];
            #pragma unroll
            for (int bb = 0; bb < TILE_O; ++bb) xacc[bb] = bini;
            #pragma unroll 4
            for (int k = 0; k < IN_DIM; ++k) {
                float wv = wc[(size_t)k * EMBED + o];
                #pragma unroll
                for (int bb = 0; bb < TILE_O; ++bb)
                    xacc[bb] = fmaf(obs_s[bb][k], wv, xacc[bb]);
            }
            #pragma unroll
            for (int bb = 0; bb < TILE_O; ++bb) x_s[bb][o] = xacc[bb];
            __syncthreads();

            float tacc[TILE_O];
            #pragma unroll
            for (int bb = 0; bb < TILE_O; ++bb) tacc[bb] = 0.f;
            #pragma unroll 4
            for (int k = 0; k < EMBED; ++k) {
                float wv = mode_W[(size_t)k * EMBED + o];
                #pragma unroll
                for (int bb = 0; bb < TILE_O; ++bb)
                    tacc[bb] = fmaf(x_s[bb][k], wv, tacc[bb]);
            }
            #pragma unroll
            for (int bb = 0; bb < TILE_O; ++bb) {
                int rid = rid_s[bb];
                if (rid >= 0) {
                    float* op = out0 + (size_t)rid * NMODES * EMBED;
                    for (int m = 0; m < NMODES; ++m)
                        st_nt(&op[m * EMBED + o], tacc[bb] + pj[m * EMBED + o]);
                }
            }
            __syncthreads();
        }
        return;
    }

    // ================= gemv path: 2-term MFMA, depth-2 prefetch ===============
    const int g = blockIdx.x - OGRID;
    const int c = (g * NEXP) / GRID2;
    const int cstart = (c * GRID2 + NEXP - 1) / NEXP;
    const int cend = ((c + 1) * GRID2 + NEXP - 1) / NEXP;
    const int blk = g - cstart;
    const int nblk = cend - cstart;
    const int cnt = counts[c];
    const int ntiles = (cnt + TM - 1) / TM;

    __shared__ int rids_s[MAXT * TM];

    if (blk >= ntiles || cnt == 0) return;
    const int nt = min((ntiles - blk + nblk - 1) / nblk, MAXT);

    const int ch = t >> 6;
    const int l = t & 63;
    const int* mylist = lists + (size_t)c * NROWS;
    const int kc = (l >> 4) * 8;

    for (int i = t; i < nt * TM; i += 256) {
        int j = i >> 4, r = i & 15;
        int gi = (blk + j * nblk) * TM + r;
        rids_s[i] = mylist[min(gi, cnt - 1)];
    }

    // hi-part weights: 48 VGPR, pinned
    bf16x8 wh[3][4];
    {
        #pragma unroll
        for (int ks = 0; ks < 3; ++ks)
            #pragma unroll
            for (int cf = 0; cf < 4; ++cf) {
                size_t base = ((((size_t)(c * 3 + ks) * 16) + (ch * 4 + cf)) * 64 + l) * 8;
                wh[ks][cf] = *reinterpret_cast<const bf16x8*>(wfrag + base);
            }
    }
    #pragma unroll
    for (int ks = 0; ks < 3; ++ks)
        #pragma unroll
        for (int cf = 0; cf < 4; ++cf) {
            i32x4 th = __builtin_bit_cast(i32x4, wh[ks][cf]);
            asm volatile("" : "+v"(th));
            wh[ks][cf] = __builtin_bit_cast(bf16x8, th);
        }
    float bias[4];
    #pragma unroll
    for (int cf = 0; cf < 4; ++cf) {
        bias[cf] = nei_b[c * EMBED + (ch * 4 + cf) * 16 + (l & 15)];
        asm volatile("" : "+v"(bias[cf]));
    }
    __syncthreads();

#define LOADJ(F, R, J) {                                                      \
    R = rids_s[(J) * TM + (l & 15)];                                          \
    const float* bp_ = neis + (size_t)(unsigned)R * IN_DIM;                   \
    _Pragma("unroll")                                                         \
    for (int ks_ = 0; ks_ < 3; ++ks_) {                                       \
        int k0_ = ks_ * 32 + kc;                                              \
        if (k0_ + 8 > IN_DIM) k0_ = 0; /* B frag is zero for k>=80 */         \
        *reinterpret_cast<float4*>(&F[ks_ * 8])     = *reinterpret_cast<const float4*>(bp_ + k0_);     \
        *reinterpret_cast<float4*>(&F[ks_ * 8 + 4]) = *reinterpret_cast<const float4*>(bp_ + k0_ + 4); \
    } }

#define COMPJ(F, R, J) {                                                      \
    bf16x8 ah_[3], al_[3];                                                    \
    _Pragma("unroll")                                                         \
    for (int ks_ = 0; ks_ < 3; ++ks_) {                                       \
        _Pragma("unroll")                                                     \
        for (int j_ = 0; j_ < 8; ++j_) {                                      \
            float v_ = F[ks_ * 8 + j_];                                       \
            float d_ = (v_ >= 0.f) ? (v_ + 1e-4f) : (v_ - 1e-4f);             \
            float r_ = __builtin_amdgcn_rcpf(d_);                             \
            unsigned short hi_ = bf16_rne(r_);                                \
            ah_[ks_][j_] = (short)hi_;                                        \
            al_[ks_][j_] = (short)bf16_rne(r_ - bf16_to_f(hi_));              \
        }                                                                     \
    }                                                                         \
    f32x4 acc_[4];                                                            \
    _Pragma("unroll")                                                         \
    for (int cf_ = 0; cf_ < 4; ++cf_) acc_[cf_] = (f32x4){0.f, 0.f, 0.f, 0.f};\
    _Pragma("unroll")                                                         \
    for (int ks_ = 0; ks_ < 3; ++ks_) {                                       \
        _Pragma("unroll")                                                     \
        for (int cf_ = 0; cf_ < 4; ++cf_) {                                   \
            acc_[cf_] = __builtin_amdgcn_mfma_f32_16x16x32_bf16(ah_[ks_], wh[ks_][cf_], acc_[cf_], 0, 0, 0); \
            acc_[cf_] = __builtin_amdgcn_mfma_f32_16x16x32_bf16(al_[ks_], wh[ks_][cf_], acc_[cf_], 0, 0, 0); \
        }                                                                     \
    }                                                                         \
    int rb_ = (l >> 4) * 4;                                                   \
    int tbase_ = (blk + (J) * nblk) * TM;                                     \
    _Pragma("unroll")                                                         \
    for (int i_ = 0; i_ < 4; ++i_) {                                          \
        int rid_ = rids_s[(J) * TM + rb_ + i_];                               \
        if (tbase_ + rb_ + i_ < cnt) {                                        \
            float* op_ = out_n + (size_t)(unsigned)rid_ * EMBED + (l & 15);   \
            _Pragma("unroll")                                                 \
            for (int cf_ = 0; cf_ < 4; ++cf_)                                 \
                op_[(ch * 4 + cf_) * 16] = acc_[cf_][i_] + bias[cf_];         \
        }                                                                     \
    } }

    float fA[24], fB[24], fC[24];
    int ridA, ridB, ridC;
    LOADJ(fA, ridA, 0)
    if (nt > 1) LOADJ(fB, ridB, 1)
    int j = 0;
    while (true) {
        if (j + 2 < nt) LOADJ(fC, ridC, j + 2)
        COMPJ(fA, ridA, j)
        if (j + 1 >= nt) break;
        if (j + 3 < nt) LOADJ(fA, ridA, j + 3)
        COMPJ(fB, ridB, j + 1)
        if (j + 2 >= nt) break;
        if (j + 4 < nt) LOADJ(fB, ridB, j + 4)
        COMPJ(fC, ridC, j + 2)
        if (j + 3 >= nt) break;
        j += 3;
    }
#undef LOADJ
#undef COMPJ
}

extern "C" void kernel_launch(void* const* d_in, const int* in_sizes, int n_in,
                              void* d_out, int out_size, void* d_ws, size_t ws_size,
                              hipStream_t stream) {
    const float* obs         = (const float*)d_in[0];
    const float* neis        = (const float*)d_in[1];
    const int*   self_labels = (const int*)d_in[2];
    const int*   nei_labels  = (const int*)d_in[3];
    const float* modes       = (const float*)d_in[4];
    const float* obs_W       = (const float*)d_in[5];
    const float* obs_b       = (const float*)d_in[6];
    const float* nei_W       = (const float*)d_in[7];
    const float* nei_b       = (const float*)d_in[8];
    const float* mode_W      = (const float*)d_in[9];
    const float* mode_b      = (const float*)d_in[10];

    float* out0  = (float*)d_out;
    float* out_n = out0 + (size_t)BATCH * NMODES * EMBED;

    char* ws = (char*)d_ws;
    int* counts   = (int*)ws;                                      // 24 B
    int* counts_o = (int*)(ws + 64);                               // 20 B
    int* lists    = (int*)(ws + 256);                              // 3 MiB
    size_t off = 256 + (size_t)NEXP * NROWS * 4;
    int* lists_o = (int*)(ws + off);                               // 40 KiB
    off += (size_t)NCLS * BATCH * 4;
    float* proj = (float*)(ws + off);                              // 100 KiB
    off += (size_t)NCLS * NMODES * EMBED * 4;
    unsigned short* wfrag = (unsigned short*)(ws + off);           // 288 KiB

    hipMemsetAsync(ws, 0, 128, stream);   // counts + counts_o

    prep_all<<<NBIN + NWF + NPRJ4 + NOB, 256, 0, stream>>>(
        nei_labels, self_labels, counts, lists, counts_o, lists_o,
        nei_W, wfrag, modes, mode_W, mode_b, proj);
    fused_main<<<OGRID + GRID2, 256, 0, stream>>>(
        obs, neis, counts_o, lists_o, counts, lists,
        obs_W, obs_b, mode_W, proj, wfrag, nei_b, out0, out_n);
}